// Round 27
// baseline (10886.462 us; speedup 1.0000x reference)
//
#include <hip/hip_runtime.h>

// All ops except the two deliberate FMAs below are per-op rounded.
#pragma clang fp contract(off)

#define BATCH 32
#define NPTS 100000
#define NGROUP 2048
#define NBLK_PER_BATCH 8
#define NPB (NPTS / NBLK_PER_BATCH)   /* 12500 points per block */
#define TPB 512
#define NPT 25                        /* staging: ceil(12500/512) writes/thread */
#define TAIL (NPB - (NPT - 1) * TPB)  /* 212 */
#define NQUAD 7                       /* compute: quads of 4 consecutive pts */
#define QTOT (NPB / 4)                /* 3125 quads, exact */
#define QTAIL (QTOT - (NQUAD - 1) * TPB) /* 53 */

typedef unsigned long long u64;
typedef unsigned int u32;

static_assert(NPB * NBLK_PER_BATCH == NPTS, "block split must be exact");
static_assert(QTOT * 4 == NPB, "quad split must be exact");

__device__ __forceinline__ float fsub_x(float a, float b) {
  float r; asm("v_sub_f32 %0, %1, %2" : "=v"(r) : "v"(a), "v"(b)); return r;
}
__device__ __forceinline__ float fmul_x(float a, float b) {
  float r; asm("v_mul_f32 %0, %1, %2" : "=v"(r) : "v"(a), "v"(b)); return r;
}
__device__ __forceinline__ float fma_x(float a, float b, float c) {
  float r; asm("v_fma_f32 %0, %1, %2, %3" : "=v"(r) : "v"(a), "v"(b), "v"(c)); return r;
}

#define LD_WG(p)    __hip_atomic_load((p),  __ATOMIC_RELAXED, __HIP_MEMORY_SCOPE_WORKGROUP)
#define ST_WG(p,v)  __hip_atomic_store((p), (v), __ATOMIC_RELAXED, __HIP_MEMORY_SCOPE_WORKGROUP)
#define LD_AG(p)    __hip_atomic_load((p),  __ATOMIC_RELAXED, __HIP_MEMORY_SCOPE_AGENT)
#define ST_AG(p,v)  __hip_atomic_store((p), (v), __ATOMIC_RELAXED, __HIP_MEMORY_SCOPE_AGENT)

// R26 post-mortem: volatile = system-class ops (HBM traffic) -> no L2 fast
// path exists. This round attacks the intra-block reduce instead:
//  - packed candidate now carries the tag in bits 63:49:
//       pk = tag<<49 | distbits<<17 | (~idx & 0x1FFFF)
//    monotone across iterations -> ONE LDS smax word, no reset, no parity.
//  - wave-wide atomicMax(&smax, pk): one ds_max_u64 folds all 64 lanes in HW,
//    replacing the 6-step u64 shuffle chain (2 ds_bpermute each, ~0.2us).
//  - monotone LDS counter scnt (8 adds/iter, target 8*(t+1)) replaces
//    barrier #1 + sval gather; tagged 3-word release replaces barrier #2
//    (spin runs only while wid0 does the global exchange — no compute
//    concurrent, so R20's LDS-spin starvation doesn't apply).
// Global exchange = R24: 8 agent slots/batch (parity kept), wid0-only
// publish+poll, speculative coord prefetch. memset 0xFF -> tag 0x7FFF.
__global__ __launch_bounds__(TPB, 1)
void fps_kernel(const float* __restrict__ xyz,
                const int* __restrict__ finit,
                float* __restrict__ out,
                u64* __restrict__ slots)
{
  const int blk  = blockIdx.x;
  const int b    = blk & (BATCH - 1);   // batch id
  const int j    = blk >> 5;            // sub-block 0..7 within batch
  const int tid  = threadIdx.x;
  const int lane = tid & 63;
  const int wid  = tid >> 6;

  __shared__ __align__(16) float sx[NPB];   // 50,000 B per plane
  __shared__ __align__(16) float sy[NPB];
  __shared__ __align__(16) float sz[NPB];
  __shared__ u64 smax;      // monotone tagged max (tag in high bits)
  __shared__ u32 scnt;      // monotone arrival counter (8 per iteration)
  __shared__ u64 srel[3];   // tagged release words: coordbits<<32 | tag

  if (tid == 0) { smax = 0ull; scnt = 0u; }
  if (tid >= 1 && tid < 4) srel[tid - 1] = ~0ull;   // tag 0x7FFF = invalid

  const float* xb = xyz + (size_t)b * NPTS * 3;
  const int base = j * NPB;

  // stage this block's 12500-point coord slice into LDS (once)
#pragma unroll
  for (int i = 0; i < NPT; ++i) {
    const bool valid = (i < NPT - 1) || (tid < TAIL);
    const int p = tid + i * TPB;
    if (valid) {
      const int gp = base + p;
      sx[p] = xb[gp * 3 + 0];
      sy[p] = xb[gp * 3 + 1];
      sz[p] = xb[gp * 3 + 2];
    }
  }
  // register-resident running min distance; sentinel -1 beyond QTOT
  float pd[NQUAD * 4];
#pragma unroll
  for (int q = 0; q < NQUAD; ++q) {
    const bool vq = (q < NQUAD - 1) || (tid < QTAIL);
#pragma unroll
    for (int k = 0; k < 4; ++k) pd[q * 4 + k] = vq ? 1.0e10f : -1.0f;
  }
  __syncthreads();   // one-time: LDS coords + control words ready

  const int cur0 = finit[b];   // int32 delivery (established R8==R5, R1==R2)
  float cx = xb[cur0 * 3 + 0], cy = xb[cur0 * 3 + 1], cz = xb[cur0 * 3 + 2];

  u64* gs = slots + (size_t)b * 2 * NBLK_PER_BATCH;   // [parity][block]

  for (int t = 0; t < NGROUP; ++t) {
    // record current farthest (pre-update); off wave 0's critical path
    if (j == 0 && wid == 1 && lane == 0) {
      float* o = out + ((size_t)b * NGROUP + t) * 3;
      o[0] = cx; o[1] = cy; o[2] = cz;
    }
    if (t == NGROUP - 1) break;   // uniform exit

    const u32 tag = (u32)t;       // t <= 2046 < 2^15
    u64* line = gs + (t & 1) * NBLK_PER_BATCH;

    // --- distance min-update + thread-local argmax (first-max wins) ---
    float bestv = -1.0f;
    int   besti = 0x7fffffff;
#pragma unroll
    for (int q = 0; q < NQUAD; ++q) {
      int qi = tid + q * TPB;
      if (q == NQUAD - 1 && tid >= QTAIL) qi = 0;   // clamped; pd slots = -1
      const int pb = qi * 4;
      const float4 vx = *(const float4*)&sx[pb];    // ds_read_b128 x3
      const float4 vy = *(const float4*)&sy[pb];
      const float4 vz = *(const float4*)&sz[pb];
#define POINT(K, XK, YK, ZK)                                                  \
      {                                                                       \
        const float dx = fsub_x(XK, cx);                                      \
        const float dy = fsub_x(YK, cy);                                      \
        const float dz = fsub_x(ZK, cz);                                      \
        const float d  = fma_x(dz, dz, fma_x(dy, dy, fmul_x(dx, dx)));        \
        const float nd = fminf(pd[q * 4 + K], d);                             \
        pd[q * 4 + K] = nd;                                                   \
        if (nd > bestv) { bestv = nd; besti = base + pb + K; }                \
      }
      POINT(0, vx.x, vy.x, vz.x)
      POINT(1, vx.y, vy.y, vz.y)
      POINT(2, vx.z, vy.z, vz.z)
      POINT(3, vx.w, vy.w, vz.w)
#undef POINT
    }

    // --- wave-wide HW reduce: one ds_max_u64 folds all 64 lanes ---
    // bestv >= 0 always (every thread owns >= 24 real points), so distbits
    // fit bits 48:17 and the tagged pack is monotone in t.
    const u64 pk = ((u64)tag << 49)
                 | ((u64)__float_as_uint(bestv) << 17)
                 | (u64)((~(u32)besti) & 0x1FFFFu);
    atomicMax((u64*)&smax, pk);
    __threadfence_block();            // wave's ds_max committed before count
    if (lane == 0) atomicAdd((u32*)&scnt, 1u);

    float ncx, ncy, ncz;
    if (wid == 0) {
      // --- wait for all 8 waves (single-word LDS spin, broadcast read) ---
      const u32 want = 8u * (u32)(t + 1);
      while (LD_WG(&scnt) != want) {}
      const u64 sv = LD_WG(&smax);    // block candidate (tagged)

      // --- publish block candidate, poll the batch's 64B slot line ---
      if (lane == 0) ST_AG(line + j, sv);
      u64 gv;
      do {
        gv = (lane < NBLK_PER_BATCH) ? LD_AG(line + lane) : 0ull;
      } while (!__all(lane >= NBLK_PER_BATCH || ((u32)(gv >> 49) == tag)));

      // --- speculative coord prefetch for the 8 candidates ---
      float fx = 0.f, fy = 0.f, fz = 0.f;
      if (lane < NBLK_PER_BATCH) {
        const int cand = (int)((~(u32)gv) & 0x1FFFFu);
        const float* cp = xb + (size_t)cand * 3;
        fx = cp[0]; fy = cp[1]; fz = cp[2];
      }
      u64 win = gv;   // lanes >= 8 hold 0 (can never win)
#pragma unroll
      for (int off = 4; off > 0; off >>= 1) {
        const u64 o = __shfl_xor(win, off, 64);
        if (o > win) win = o;
      }
      const u64 wmax = __shfl(win, 0, 64);
      const u64 mask = __ballot(lane < NBLK_PER_BATCH && gv == wmax);
      const int w    = (int)__ffsll((long long)mask) - 1;
      ncx = __shfl(fx, w, 64); ncy = __shfl(fy, w, 64); ncz = __shfl(fz, w, 64);

      // --- release the block: 3 tagged LDS words (no barrier) ---
      if (lane == 0) {
        ST_WG(&srel[0], ((u64)__float_as_uint(ncx) << 32) | tag);
        ST_WG(&srel[1], ((u64)__float_as_uint(ncy) << 32) | tag);
        ST_WG(&srel[2], ((u64)__float_as_uint(ncz) << 32) | tag);
      }
    } else {
      // --- spin on release (runs only while wid0 does the global exchange;
      //     no concurrent compute to starve) ---
      u64 rv;
      do {
        rv = (lane < 3) ? LD_WG(&srel[lane]) : 0ull;
      } while (!__all(lane >= 3 || (((u32)rv & 0x7FFFu) == (tag & 0x7FFFu))));
      const float f = __uint_as_float((u32)(rv >> 32));
      ncx = __shfl(f, 0, 64); ncy = __shfl(f, 1, 64); ncz = __shfl(f, 2, 64);
    }

    cx = ncx; cy = ncy; cz = ncz;
  }
}

extern "C" void kernel_launch(void* const* d_in, const int* in_sizes, int n_in,
                              void* d_out, int out_size, void* d_ws, size_t ws_size,
                              hipStream_t stream) {
  const float* xyz   = (const float*)d_in[0];
  const int*   finit = (const int*)d_in[1];
  float*       out   = (float*)d_out;
  u64*         slots = (u64*)d_ws;   // 32 x 2 x 8 u64 = 4 KB exchange slots

  // Invalidate all global slots every call (tag field -> 0x7FFF, never a
  // valid iteration tag).
  hipMemsetAsync(d_ws, 0xFF,
                 (size_t)BATCH * 2 * NBLK_PER_BATCH * sizeof(u64), stream);

  fps_kernel<<<dim3(BATCH * NBLK_PER_BATCH), dim3(TPB), 0, stream>>>(xyz, finit, out, slots);
}